// Round 1
// baseline (399.926 us; speedup 1.0000x reference)
//
#include <hip/hip_runtime.h>
#include <hip/hip_bf16.h>
#include <math.h>

// Problem constants (from reference): N=10000, E=160000, D=128, H=4, C=128, HC=512
#define D_DIM 128
#define HC_DIM 512

// ---------------------------------------------------------------------------
// GEMM: out[N x M] = A[N x 128] @ W[128 x M] + bias[M]   (fp32, vector ALU)
// Tile 128x128, 256 threads, 8x8 per thread, K-chunks of 16 staged in LDS.
// ---------------------------------------------------------------------------
__global__ __launch_bounds__(256) void gemm128_kernel(
    const float* __restrict__ A, const float* __restrict__ W,
    const float* __restrict__ bias, float* __restrict__ out, int N, int M) {
  __shared__ float As[16][132];  // [k][row], padded (132*4B keeps 16B align)
  __shared__ float Bs[16][132];  // [k][col]
  const int row0 = blockIdx.x * 128;
  const int col0 = blockIdx.y * 128;
  const int tid = threadIdx.x;
  const int tr = tid >> 4;   // 0..15 -> rows tr*8..tr*8+7
  const int tc = tid & 15;   // 0..15 -> cols tc*8..tc*8+7
  float acc[8][8];
#pragma unroll
  for (int i = 0; i < 8; ++i)
#pragma unroll
    for (int j = 0; j < 8; ++j) acc[i][j] = 0.f;

  for (int k0 = 0; k0 < 128; k0 += 16) {
    // Load A tile: 128 rows x 16 k. 512 float4s total, 2 per thread.
#pragma unroll
    for (int i = 0; i < 2; ++i) {
      int fid = tid * 2 + i;          // 0..511
      int r = fid >> 2;               // 0..127
      int kk4 = (fid & 3) * 4;        // 0,4,8,12
      int gr = row0 + r;
      float4 a; a.x = a.y = a.z = a.w = 0.f;
      if (gr < N) a = *(const float4*)&A[(size_t)gr * 128 + k0 + kk4];
      As[kk4 + 0][r] = a.x; As[kk4 + 1][r] = a.y;
      As[kk4 + 2][r] = a.z; As[kk4 + 3][r] = a.w;
    }
    // Load B tile: 16 k x 128 cols. 512 float4s, 2 per thread.
#pragma unroll
    for (int i = 0; i < 2; ++i) {
      int fid = tid * 2 + i;
      int kk = fid >> 5;              // 0..15
      int c4 = (fid & 31) * 4;        // 0..124
      float4 b = *(const float4*)&W[(size_t)(k0 + kk) * M + col0 + c4];
      *(float4*)&Bs[kk][c4] = b;
    }
    __syncthreads();
#pragma unroll
    for (int kk = 0; kk < 16; ++kk) {
      float a[8], b[8];
      *(float4*)&a[0] = *(const float4*)&As[kk][tr * 8];
      *(float4*)&a[4] = *(const float4*)&As[kk][tr * 8 + 4];
      *(float4*)&b[0] = *(const float4*)&Bs[kk][tc * 8];
      *(float4*)&b[4] = *(const float4*)&Bs[kk][tc * 8 + 4];
#pragma unroll
      for (int i = 0; i < 8; ++i)
#pragma unroll
        for (int j = 0; j < 8; ++j) acc[i][j] += a[i] * b[j];
    }
    __syncthreads();
  }
#pragma unroll
  for (int i = 0; i < 8; ++i) {
    int r = row0 + tr * 8 + i;
    if (r < N) {
#pragma unroll
      for (int j = 0; j < 8; ++j) {
        int c = col0 + tc * 8 + j;
        out[(size_t)r * M + c] = acc[i][j] + bias[c];
      }
    }
  }
}

// ---------------------------------------------------------------------------
// Edge bucketing: histogram of dst, exclusive scan, scatter src into buckets
// ---------------------------------------------------------------------------
__global__ void hist_kernel(const int* __restrict__ dst, int* __restrict__ cnt, int E) {
  int e = blockIdx.x * 256 + threadIdx.x;
  if (e < E) atomicAdd(&cnt[dst[e]], 1);
}

__global__ __launch_bounds__(256) void scan_kernel(const int* __restrict__ cnt,
                                                   int* __restrict__ off, int n) {
  __shared__ int buf[256];
  __shared__ int carry;
  int tid = threadIdx.x;
  if (tid == 0) carry = 0;
  __syncthreads();
  for (int base = 0; base < n; base += 256) {
    int i = base + tid;
    int v = (i < n) ? cnt[i] : 0;
    buf[tid] = v;
    __syncthreads();
    for (int s = 1; s < 256; s <<= 1) {
      int add = (tid >= s) ? buf[tid - s] : 0;
      __syncthreads();
      buf[tid] += add;
      __syncthreads();
    }
    int incl = buf[tid];
    int c = carry;
    if (i < n) off[i] = c + incl - v;  // exclusive prefix
    __syncthreads();
    if (tid == 255) carry = c + buf[255];
    __syncthreads();
  }
  if (tid == 0) off[n] = carry;
}

__global__ void scatter_kernel(const int* __restrict__ src, const int* __restrict__ dst,
                               const int* __restrict__ off, int* __restrict__ cur,
                               int* __restrict__ bsrc, int E) {
  int e = blockIdx.x * 256 + threadIdx.x;
  if (e < E) {
    int d = dst[e];
    int p = off[d] + atomicAdd(&cur[d], 1);
    bsrc[p] = src[e];
  }
}

// ---------------------------------------------------------------------------
// Attention: one block per dst node; wave w = head h; lanes split C=128.
// Online softmax over the node's incoming edges; head-mean written out.
// ---------------------------------------------------------------------------
__global__ __launch_bounds__(256) void attn_kernel(
    const float* __restrict__ q, const float* __restrict__ k,
    const float* __restrict__ v, const int* __restrict__ off,
    const int* __restrict__ bsrc, float* __restrict__ outa, int N) {
  int node = blockIdx.x;
  int tid = threadIdx.x;
  int h = tid >> 6;
  int lane = tid & 63;
  const float* qp = q + (size_t)node * HC_DIM + h * 128;
  float q0 = qp[lane], q1 = qp[lane + 64];
  int beg = off[node], end = off[node + 1];
  float m = -INFINITY, lsum = 0.f, o0 = 0.f, o1 = 0.f;
  for (int idx = beg; idx < end; ++idx) {
    int s = bsrc[idx];
    const float* kp = k + (size_t)s * HC_DIM + h * 128;
    float partial = q0 * kp[lane] + q1 * kp[lane + 64];
#pragma unroll
    for (int dmask = 1; dmask < 64; dmask <<= 1) partial += __shfl_xor(partial, dmask);
    float alpha = partial * 0.08838834764831845f;  // 1/sqrt(128)
    float mnew = fmaxf(m, alpha);
    float corr = expf(m - mnew);   // first iter: exp(-inf)=0
    float w = expf(alpha - mnew);
    const float* vp = v + (size_t)s * HC_DIM + h * 128;
    lsum = lsum * corr + w;
    o0 = o0 * corr + w * vp[lane];
    o1 = o1 * corr + w * vp[lane + 64];
    m = mnew;
  }
  // reference: attn = ex / (denom + 1e-16) in the max-shifted domain
  float den = lsum + 1e-16f;
  o0 /= den;
  o1 /= den;
  __shared__ float tmp[4][128];
  tmp[h][lane] = o0;
  tmp[h][lane + 64] = o1;
  __syncthreads();
  if (tid < 128) {
    float s = 0.25f * (tmp[0][tid] + tmp[1][tid] + tmp[2][tid] + tmp[3][tid]);
    outa[(size_t)node * 128 + tid] = s;
  }
}

// ---------------------------------------------------------------------------
// beta gate + out2 + column sums (for axis-0 mean/var)
// ---------------------------------------------------------------------------
__global__ __launch_bounds__(128) void combine_kernel(
    const float* __restrict__ outa, const float* __restrict__ skip,
    const float* __restrict__ Wbeta, float* __restrict__ out2,
    float* __restrict__ colsum, float* __restrict__ colsq, int N) {
  int t = threadIdx.x;  // 0..127 = column
  float wb0 = Wbeta[t], wb1 = Wbeta[128 + t], wb2 = Wbeta[256 + t];
  float cs = 0.f, cq = 0.f;
  __shared__ float red[2];
  int lane = t & 63, wid = t >> 6;
  for (int n = blockIdx.x; n < N; n += gridDim.x) {
    float a = outa[(size_t)n * 128 + t];
    float s = skip[(size_t)n * 128 + t];
    float p = a * wb0 + s * wb1 + (a - s) * wb2;
#pragma unroll
    for (int dmask = 1; dmask < 64; dmask <<= 1) p += __shfl_xor(p, dmask);
    if (lane == 0) red[wid] = p;
    __syncthreads();
    float z = red[0] + red[1];
    float beta = 1.f / (1.f + expf(-z));
    float o = beta * s + (1.f - beta) * a;
    out2[(size_t)n * 128 + t] = o;
    cs += o;
    cq += o * o;
    __syncthreads();  // red reused next iteration
  }
  atomicAdd(&colsum[t], cs);
  atomicAdd(&colsq[t], cq);
}

// ---------------------------------------------------------------------------
// finalize per-column stats:
// var = E[o^2] - mean^2 * s * (2 - s)   (exact expansion of E[(o - s*mean)^2])
// ---------------------------------------------------------------------------
__global__ void stats_kernel(const float* __restrict__ colsum,
                             const float* __restrict__ colsq,
                             const float* __restrict__ gnw,
                             const float* __restrict__ gnb,
                             const float* __restrict__ gnms,
                             float* __restrict__ fin, int N) {
  int t = threadIdx.x;  // 128 threads
  float invN = 1.f / (float)N;
  float mean = colsum[t] * invN;
  float Es = colsq[t] * invN;
  float s = gnms[t];
  float var = Es - mean * mean * s * (2.f - s);
  float inv = 1.f / sqrtf(var + 1e-5f);
  fin[t] = s * mean;             // subtract
  fin[128 + t] = gnw[t] * inv;   // multiply
  fin[256 + t] = gnb[t];         // add
}

// ---------------------------------------------------------------------------
// normalize + exact GELU + residual
// ---------------------------------------------------------------------------
__global__ void final_kernel(const float* __restrict__ out2,
                             const float* __restrict__ fin,
                             const float* __restrict__ x,
                             float* __restrict__ y, int total) {
  int i = blockIdx.x * 256 + threadIdx.x;
  if (i < total) {
    int c = i & 127;
    float o = out2[i];
    float t = (o - fin[c]) * fin[128 + c] + fin[256 + c];
    float g = 0.5f * t * (1.f + erff(t * 0.70710678118654752f));
    y[i] = g + x[i];
  }
}

extern "C" void kernel_launch(void* const* d_in, const int* in_sizes, int n_in,
                              void* d_out, int out_size, void* d_ws, size_t ws_size,
                              hipStream_t stream) {
  const float* x     = (const float*)d_in[0];
  const int*   ei    = (const int*)d_in[1];
  const float* Wq    = (const float*)d_in[2];
  const float* bq    = (const float*)d_in[3];
  const float* Wk    = (const float*)d_in[4];
  const float* bk    = (const float*)d_in[5];
  const float* Wv    = (const float*)d_in[6];
  const float* bv    = (const float*)d_in[7];
  const float* Wskip = (const float*)d_in[8];
  const float* bskip = (const float*)d_in[9];
  const float* Wbeta = (const float*)d_in[10];
  const float* gnw   = (const float*)d_in[11];
  const float* gnb   = (const float*)d_in[12];
  const float* gnms  = (const float*)d_in[13];

  const int N = in_sizes[0] / D_DIM;   // 10000
  const int E = in_sizes[1] / 2;       // 160000
  const int* src = ei;
  const int* dst = ei + E;

  // workspace carve-up
  char* p = (char*)d_ws;
  float* q    = (float*)p; p += (size_t)N * HC_DIM * 4;
  float* k    = (float*)p; p += (size_t)N * HC_DIM * 4;
  float* v    = (float*)p; p += (size_t)N * HC_DIM * 4;
  float* skip = (float*)p; p += (size_t)N * D_DIM * 4;
  float* outa = (float*)p; p += (size_t)N * D_DIM * 4;
  float* out2 = (float*)p; p += (size_t)N * D_DIM * 4;
  float* colsum = (float*)p; p += 128 * 4;
  float* colsq  = (float*)p; p += 128 * 4;
  float* fin    = (float*)p; p += 384 * 4;
  int* cnt  = (int*)p; p += (size_t)N * 4;
  int* off  = (int*)p; p += (size_t)(N + 1) * 4;
  int* cur  = (int*)p; p += (size_t)N * 4;
  int* bsrc = (int*)p; p += (size_t)E * 4;

  // zero accumulators / counters
  hipMemsetAsync(cnt, 0, (size_t)N * 4, stream);
  hipMemsetAsync(cur, 0, (size_t)N * 4, stream);
  hipMemsetAsync(colsum, 0, 128 * 4, stream);
  hipMemsetAsync(colsq, 0, 128 * 4, stream);

  const int rowBlocks = (N + 127) / 128;  // 79

  // projections
  gemm128_kernel<<<dim3(rowBlocks, HC_DIM / 128), 256, 0, stream>>>(x, Wq, bq, q, N, HC_DIM);
  gemm128_kernel<<<dim3(rowBlocks, HC_DIM / 128), 256, 0, stream>>>(x, Wk, bk, k, N, HC_DIM);
  gemm128_kernel<<<dim3(rowBlocks, HC_DIM / 128), 256, 0, stream>>>(x, Wv, bv, v, N, HC_DIM);
  gemm128_kernel<<<dim3(rowBlocks, 1), 256, 0, stream>>>(x, Wskip, bskip, skip, N, D_DIM);

  // bucket edges by dst
  int eBlocks = (E + 255) / 256;
  hist_kernel<<<eBlocks, 256, 0, stream>>>(dst, cnt, E);
  scan_kernel<<<1, 256, 0, stream>>>(cnt, off, N);
  scatter_kernel<<<eBlocks, 256, 0, stream>>>(src, dst, off, cur, bsrc, E);

  // attention
  attn_kernel<<<N, 256, 0, stream>>>(q, k, v, off, bsrc, outa, N);

  // beta gate + column moments
  combine_kernel<<<240, 128, 0, stream>>>(outa, skip, Wbeta, out2, colsum, colsq, N);

  // stats + finalize
  stats_kernel<<<1, 128, 0, stream>>>(colsum, colsq, gnw, gnb, gnms, fin, N);
  int total = N * D_DIM;
  final_kernel<<<(total + 255) / 256, 256, 0, stream>>>(out2, fin, x, (float*)d_out, total);
}

// Round 2
// 316.699 us; speedup vs baseline: 1.2628x; 1.2628x over previous
//
#include <hip/hip_runtime.h>
#include <hip/hip_bf16.h>
#include <math.h>

// Problem constants: N=10000, E=160000, D=128, H=4, C=128, HC=512
#define D_DIM 128
#define HC_DIM 512

typedef __attribute__((ext_vector_type(8))) short bf16x8;
typedef __attribute__((ext_vector_type(4))) float f32x4;

static __device__ __forceinline__ unsigned short f2bf(float f) {
  unsigned u = __float_as_uint(f);
  unsigned r = (u + 0x7fffu + ((u >> 16) & 1u)) >> 16;  // RNE
  return (unsigned short)r;
}

// ---------------------------------------------------------------------------
// Cast x (fp32 row-major [N][128]) -> bf16, same layout
// ---------------------------------------------------------------------------
__global__ void castx_kernel(const float* __restrict__ x,
                             unsigned short* __restrict__ xb, int total4) {
  int i = blockIdx.x * 256 + threadIdx.x;
  if (i < total4) {
    float4 f = *(const float4*)&x[i * 4];
    ushort4 o;
    o.x = f2bf(f.x); o.y = f2bf(f.y); o.z = f2bf(f.z); o.w = f2bf(f.w);
    *(ushort4*)&xb[i * 4] = o;
  }
}

// ---------------------------------------------------------------------------
// Cast + transpose W (fp32 [K=128][M]) -> bf16 Wt [M][128]
// ---------------------------------------------------------------------------
__global__ void castwt_kernel(const float* __restrict__ W,
                              unsigned short* __restrict__ Wt,
                              int mlog2, int total) {
  int i = blockIdx.x * 256 + threadIdx.x;
  if (i < total) {
    int M1 = (1 << mlog2) - 1;
    int m = i & M1;
    int kk = i >> mlog2;
    Wt[m * 128 + kk] = f2bf(W[i]);  // W[kk*M + m] == W[i], coalesced read
  }
}

// ---------------------------------------------------------------------------
// MFMA GEMM: out[N x M] = Xb[N x 128](bf16) @ Wt[M x 128]^T(bf16) + bias
// 128x128 tile, 256 threads (4 waves, 2x2 of 64x64), K staged in 64-chunks.
// LDS rows padded +8 bf16 (16B) so ds_read_b128 across 16 rows is 2-way max.
// ---------------------------------------------------------------------------
__global__ __launch_bounds__(256) void gemm_mfma_kernel(
    const unsigned short* __restrict__ Xb, const unsigned short* __restrict__ Wt,
    const float* __restrict__ bias, float* __restrict__ out, int N, int M) {
  __shared__ unsigned short Xs[128][72];  // [m][k], 72*2=144B row stride
  __shared__ unsigned short Ws[128][72];  // [n][k]
  const int row0 = blockIdx.x * 128;
  const int col0 = blockIdx.y * 128;
  const int tid = threadIdx.x;
  const int wave = tid >> 6, lane = tid & 63;
  const int wr = (wave >> 1) * 64, wc = (wave & 1) * 64;
  const int l16 = lane & 15, quad = lane >> 4;

  f32x4 acc[4][4] = {};

  for (int kc = 0; kc < 128; kc += 64) {
    // stage 128x64 bf16 tiles of X and Wt: 1024 16B-chunks each, 4/thread
#pragma unroll
    for (int c = tid; c < 1024; c += 256) {
      int r = c >> 3;           // 0..127
      int k8 = (c & 7) * 8;     // 0..56
      int gr = row0 + r;
      int4 a = {0, 0, 0, 0};
      if (gr < N) a = *(const int4*)&Xb[(size_t)gr * 128 + kc + k8];
      *(int4*)&Xs[r][k8] = a;
      int gc = col0 + r;        // M is a multiple of 128
      *(int4*)&Ws[r][k8] = *(const int4*)&Wt[(size_t)gc * 128 + kc + k8];
    }
    __syncthreads();
#pragma unroll
    for (int ks = 0; ks < 2; ++ks) {
      int k0 = ks * 32 + quad * 8;
      bf16x8 a[4], b[4];
#pragma unroll
      for (int i = 0; i < 4; ++i) a[i] = *(const bf16x8*)&Xs[wr + i * 16 + l16][k0];
#pragma unroll
      for (int j = 0; j < 4; ++j) b[j] = *(const bf16x8*)&Ws[wc + j * 16 + l16][k0];
#pragma unroll
      for (int i = 0; i < 4; ++i)
#pragma unroll
        for (int j = 0; j < 4; ++j)
          acc[i][j] = __builtin_amdgcn_mfma_f32_16x16x32_bf16(a[i], b[j], acc[i][j], 0, 0, 0);
    }
    __syncthreads();
  }
  // C/D layout: col = lane&15, row = quad*4 + reg  [m89-verified]
#pragma unroll
  for (int i = 0; i < 4; ++i) {
#pragma unroll
    for (int reg = 0; reg < 4; ++reg) {
      int r = row0 + wr + i * 16 + quad * 4 + reg;
      if (r < N) {
#pragma unroll
        for (int j = 0; j < 4; ++j) {
          int cidx = col0 + wc + j * 16 + l16;
          out[(size_t)r * M + cidx] = acc[i][j][reg] + bias[cidx];
        }
      }
    }
  }
}

// ---------------------------------------------------------------------------
// Edge bucketing
// ---------------------------------------------------------------------------
__global__ void hist_kernel(const int* __restrict__ dst, int* __restrict__ cnt, int E) {
  int e = blockIdx.x * 256 + threadIdx.x;
  if (e < E) atomicAdd(&cnt[dst[e]], 1);
}

__global__ __launch_bounds__(256) void scan_kernel(const int* __restrict__ cnt,
                                                   int* __restrict__ off, int n) {
  __shared__ int wsum[4];
  __shared__ int carry;
  int tid = threadIdx.x;
  int lane = tid & 63, w = tid >> 6;
  if (tid == 0) carry = 0;
  __syncthreads();
  for (int base = 0; base < n; base += 256) {
    int i = base + tid;
    int vv = (i < n) ? cnt[i] : 0;
    int x = vv;
#pragma unroll
    for (int d = 1; d < 64; d <<= 1) {
      int y = __shfl_up(x, d);
      if (lane >= d) x += y;
    }
    if (lane == 63) wsum[w] = x;
    __syncthreads();
    int wo = 0;
    for (int j = 0; j < w; ++j) wo += wsum[j];
    int c = carry;
    if (i < n) off[i] = c + wo + x - vv;  // exclusive prefix
    __syncthreads();
    if (tid == 255) carry = c + wo + x;
    __syncthreads();
  }
  if (tid == 0) off[n] = carry;
}

__global__ void scatter_kernel(const int* __restrict__ src, const int* __restrict__ dst,
                               const int* __restrict__ off, int* __restrict__ cur,
                               int* __restrict__ bsrc, int E) {
  int e = blockIdx.x * 256 + threadIdx.x;
  if (e < E) {
    int d = dst[e];
    int p = off[d] + atomicAdd(&cur[d], 1);
    bsrc[p] = src[e];
  }
}

// ---------------------------------------------------------------------------
// Attention: block = dst node, wave = head, lanes split C=128 (2 floats/lane).
// 4-edge unrolled online softmax for memory-level parallelism.
// ---------------------------------------------------------------------------
__global__ __launch_bounds__(256) void attn_kernel(
    const float* __restrict__ q, const float* __restrict__ k,
    const float* __restrict__ v, const int* __restrict__ off,
    const int* __restrict__ bsrc, float* __restrict__ outa, int N) {
  int node = blockIdx.x;
  int tid = threadIdx.x;
  int h = tid >> 6;
  int lane = tid & 63;
  const float* qp = q + (size_t)node * HC_DIM + h * 128;
  float q0 = qp[lane], q1 = qp[lane + 64];
  int beg = off[node], end = off[node + 1];
  const float scale = 0.08838834764831845f;  // 1/sqrt(128)
  float m = -INFINITY, lsum = 0.f, o0 = 0.f, o1 = 0.f;
  int idx = beg;
  for (; idx + 4 <= end; idx += 4) {
    int s0 = bsrc[idx], s1 = bsrc[idx + 1], s2 = bsrc[idx + 2], s3 = bsrc[idx + 3];
    const float* kp0 = k + (size_t)s0 * HC_DIM + h * 128;
    const float* kp1 = k + (size_t)s1 * HC_DIM + h * 128;
    const float* kp2 = k + (size_t)s2 * HC_DIM + h * 128;
    const float* kp3 = k + (size_t)s3 * HC_DIM + h * 128;
    const float* vp0 = v + (size_t)s0 * HC_DIM + h * 128;
    const float* vp1 = v + (size_t)s1 * HC_DIM + h * 128;
    const float* vp2 = v + (size_t)s2 * HC_DIM + h * 128;
    const float* vp3 = v + (size_t)s3 * HC_DIM + h * 128;
    float k00 = kp0[lane], k01 = kp0[lane + 64];
    float k10 = kp1[lane], k11 = kp1[lane + 64];
    float k20 = kp2[lane], k21 = kp2[lane + 64];
    float k30 = kp3[lane], k31 = kp3[lane + 64];
    float v00 = vp0[lane], v01 = vp0[lane + 64];
    float v10 = vp1[lane], v11 = vp1[lane + 64];
    float v20 = vp2[lane], v21 = vp2[lane + 64];
    float v30 = vp3[lane], v31 = vp3[lane + 64];
    float p0 = q0 * k00 + q1 * k01;
    float p1 = q0 * k10 + q1 * k11;
    float p2 = q0 * k20 + q1 * k21;
    float p3 = q0 * k30 + q1 * k31;
#pragma unroll
    for (int dmask = 1; dmask < 64; dmask <<= 1) {
      p0 += __shfl_xor(p0, dmask);
      p1 += __shfl_xor(p1, dmask);
      p2 += __shfl_xor(p2, dmask);
      p3 += __shfl_xor(p3, dmask);
    }
    float a0 = p0 * scale, a1 = p1 * scale, a2 = p2 * scale, a3 = p3 * scale;
    float mnew = fmaxf(fmaxf(fmaxf(a0, a1), fmaxf(a2, a3)), m);
    float corr = __expf(m - mnew);  // m=-inf first iter -> 0
    float w0 = __expf(a0 - mnew), w1 = __expf(a1 - mnew);
    float w2 = __expf(a2 - mnew), w3 = __expf(a3 - mnew);
    lsum = lsum * corr + (w0 + w1) + (w2 + w3);
    o0 = o0 * corr + w0 * v00 + w1 * v10 + w2 * v20 + w3 * v30;
    o1 = o1 * corr + w0 * v01 + w1 * v11 + w2 * v21 + w3 * v31;
    m = mnew;
  }
  for (; idx < end; ++idx) {
    int s = bsrc[idx];
    const float* kp = k + (size_t)s * HC_DIM + h * 128;
    const float* vp = v + (size_t)s * HC_DIM + h * 128;
    float vv0 = vp[lane], vv1 = vp[lane + 64];
    float partial = q0 * kp[lane] + q1 * kp[lane + 64];
#pragma unroll
    for (int dmask = 1; dmask < 64; dmask <<= 1) partial += __shfl_xor(partial, dmask);
    float alpha = partial * scale;
    float mnew = fmaxf(m, alpha);
    float corr = __expf(m - mnew);
    float w = __expf(alpha - mnew);
    lsum = lsum * corr + w;
    o0 = o0 * corr + w * vv0;
    o1 = o1 * corr + w * vv1;
    m = mnew;
  }
  float den = lsum + 1e-16f;
  o0 /= den;
  o1 /= den;
  __shared__ float tmp[4][128];
  tmp[h][lane] = o0;
  tmp[h][lane + 64] = o1;
  __syncthreads();
  if (tid < 128) {
    float s = 0.25f * (tmp[0][tid] + tmp[1][tid] + tmp[2][tid] + tmp[3][tid]);
    outa[(size_t)node * 128 + tid] = s;
  }
}

// ---------------------------------------------------------------------------
// beta gate + out2 + column sums
// ---------------------------------------------------------------------------
__global__ __launch_bounds__(128) void combine_kernel(
    const float* __restrict__ outa, const float* __restrict__ skip,
    const float* __restrict__ Wbeta, float* __restrict__ out2,
    float* __restrict__ colsum, float* __restrict__ colsq, int N) {
  int t = threadIdx.x;  // column
  float wb0 = Wbeta[t], wb1 = Wbeta[128 + t], wb2 = Wbeta[256 + t];
  float cs = 0.f, cq = 0.f;
  __shared__ float red[2][2];
  int lane = t & 63, wid = t >> 6;
  int par = 0;
  for (int n = blockIdx.x; n < N; n += gridDim.x) {
    float a = outa[(size_t)n * 128 + t];
    float s = skip[(size_t)n * 128 + t];
    float p = a * wb0 + s * wb1 + (a - s) * wb2;
#pragma unroll
    for (int dmask = 1; dmask < 64; dmask <<= 1) p += __shfl_xor(p, dmask);
    if (lane == 0) red[par][wid] = p;
    __syncthreads();
    float z = red[par][0] + red[par][1];
    float beta = 1.f / (1.f + __expf(-z));
    float o = beta * s + (1.f - beta) * a;
    out2[(size_t)n * 128 + t] = o;
    cs += o;
    cq += o * o;
    par ^= 1;  // ping-pong: no second sync needed
  }
  atomicAdd(&colsum[t], cs);
  atomicAdd(&colsq[t], cq);
}

// var = E[o^2] - mean^2 * s * (2 - s)  (exact expansion with gn_mean_scale)
__global__ void stats_kernel(const float* __restrict__ colsum,
                             const float* __restrict__ colsq,
                             const float* __restrict__ gnw,
                             const float* __restrict__ gnb,
                             const float* __restrict__ gnms,
                             float* __restrict__ fin, int N) {
  int t = threadIdx.x;
  float invN = 1.f / (float)N;
  float mean = colsum[t] * invN;
  float Es = colsq[t] * invN;
  float s = gnms[t];
  float var = Es - mean * mean * s * (2.f - s);
  float inv = 1.f / sqrtf(var + 1e-5f);
  fin[t] = s * mean;
  fin[128 + t] = gnw[t] * inv;
  fin[256 + t] = gnb[t];
}

__global__ void final_kernel(const float* __restrict__ out2,
                             const float* __restrict__ fin,
                             const float* __restrict__ x,
                             float* __restrict__ y, int total) {
  int i = blockIdx.x * 256 + threadIdx.x;
  if (i < total) {
    int c = i & 127;
    float o = out2[i];
    float t = (o - fin[c]) * fin[128 + c] + fin[256 + c];
    float g = 0.5f * t * (1.f + erff(t * 0.70710678118654752f));
    y[i] = g + x[i];
  }
}

extern "C" void kernel_launch(void* const* d_in, const int* in_sizes, int n_in,
                              void* d_out, int out_size, void* d_ws, size_t ws_size,
                              hipStream_t stream) {
  const float* x     = (const float*)d_in[0];
  const int*   ei    = (const int*)d_in[1];
  const float* Wq    = (const float*)d_in[2];
  const float* bq    = (const float*)d_in[3];
  const float* Wk    = (const float*)d_in[4];
  const float* bk    = (const float*)d_in[5];
  const float* Wv    = (const float*)d_in[6];
  const float* bv    = (const float*)d_in[7];
  const float* Wskip = (const float*)d_in[8];
  const float* bskip = (const float*)d_in[9];
  const float* Wbeta = (const float*)d_in[10];
  const float* gnw   = (const float*)d_in[11];
  const float* gnb   = (const float*)d_in[12];
  const float* gnms  = (const float*)d_in[13];

  const int N = in_sizes[0] / D_DIM;   // 10000
  const int E = in_sizes[1] / 2;       // 160000
  const int* src = ei;
  const int* dst = ei + E;

  // workspace carve-up
  char* p = (char*)d_ws;
  float* q    = (float*)p; p += (size_t)N * HC_DIM * 4;
  float* k    = (float*)p; p += (size_t)N * HC_DIM * 4;
  float* v    = (float*)p; p += (size_t)N * HC_DIM * 4;
  float* skip = (float*)p; p += (size_t)N * D_DIM * 4;
  float* outa = (float*)p; p += (size_t)N * D_DIM * 4;
  float* out2 = (float*)p; p += (size_t)N * D_DIM * 4;
  float* colsum = (float*)p; p += 128 * 4;
  float* colsq  = (float*)p; p += 128 * 4;
  float* fin    = (float*)p; p += 384 * 4;
  int* cnt  = (int*)p; p += (size_t)N * 4;
  int* off  = (int*)p; p += (size_t)(N + 1) * 4;
  int* cur  = (int*)p; p += (size_t)N * 4;
  int* bsrc = (int*)p; p += (size_t)E * 4;
  unsigned short* xb  = (unsigned short*)p; p += (size_t)N * D_DIM * 2;
  unsigned short* wtq = (unsigned short*)p; p += (size_t)HC_DIM * 128 * 2;
  unsigned short* wtk = (unsigned short*)p; p += (size_t)HC_DIM * 128 * 2;
  unsigned short* wtv = (unsigned short*)p; p += (size_t)HC_DIM * 128 * 2;
  unsigned short* wts = (unsigned short*)p; p += (size_t)128 * 128 * 2;

  hipMemsetAsync(cnt, 0, (size_t)N * 4, stream);
  hipMemsetAsync(cur, 0, (size_t)N * 4, stream);
  hipMemsetAsync(colsum, 0, 128 * 4, stream);
  hipMemsetAsync(colsq, 0, 128 * 4, stream);

  // casts
  int x4 = N * D_DIM / 4;
  castx_kernel<<<(x4 + 255) / 256, 256, 0, stream>>>(x, xb, x4);
  castwt_kernel<<<(128 * HC_DIM + 255) / 256, 256, 0, stream>>>(Wq, wtq, 9, 128 * HC_DIM);
  castwt_kernel<<<(128 * HC_DIM + 255) / 256, 256, 0, stream>>>(Wk, wtk, 9, 128 * HC_DIM);
  castwt_kernel<<<(128 * HC_DIM + 255) / 256, 256, 0, stream>>>(Wv, wtv, 9, 128 * HC_DIM);
  castwt_kernel<<<(128 * 128 + 255) / 256, 256, 0, stream>>>(Wskip, wts, 7, 128 * 128);

  const int rowBlocks = (N + 127) / 128;  // 79

  // projections (MFMA)
  gemm_mfma_kernel<<<dim3(rowBlocks, HC_DIM / 128), 256, 0, stream>>>(xb, wtq, bq, q, N, HC_DIM);
  gemm_mfma_kernel<<<dim3(rowBlocks, HC_DIM / 128), 256, 0, stream>>>(xb, wtk, bk, k, N, HC_DIM);
  gemm_mfma_kernel<<<dim3(rowBlocks, HC_DIM / 128), 256, 0, stream>>>(xb, wtv, bv, v, N, HC_DIM);
  gemm_mfma_kernel<<<dim3(rowBlocks, 1), 256, 0, stream>>>(xb, wts, bskip, skip, N, D_DIM);

  // bucket edges by dst
  int eBlocks = (E + 255) / 256;
  hist_kernel<<<eBlocks, 256, 0, stream>>>(dst, cnt, E);
  scan_kernel<<<1, 256, 0, stream>>>(cnt, off, N);
  scatter_kernel<<<eBlocks, 256, 0, stream>>>(src, dst, off, cur, bsrc, E);

  // attention
  attn_kernel<<<N, 256, 0, stream>>>(q, k, v, off, bsrc, outa, N);

  // beta gate + column moments
  combine_kernel<<<640, 128, 0, stream>>>(outa, skip, Wbeta, out2, colsum, colsq, N);

  // stats + finalize
  stats_kernel<<<1, 128, 0, stream>>>(colsum, colsq, gnw, gnb, gnms, fin, N);
  int total = N * D_DIM;
  final_kernel<<<(total + 255) / 256, 256, 0, stream>>>(out2, fin, x, (float*)d_out, total);
}

// Round 3
// 255.120 us; speedup vs baseline: 1.5676x; 1.2414x over previous
//
#include <hip/hip_runtime.h>
#include <hip/hip_bf16.h>
#include <math.h>

// Problem constants: N=10000, E=160000, D=128, H=4, C=128, HC=512
#define D_DIM 128
#define HC_DIM 512

typedef __attribute__((ext_vector_type(8))) short bf16x8;
typedef __attribute__((ext_vector_type(4))) float f32x4;

static __device__ __forceinline__ unsigned short f2bf(float f) {
  unsigned u = __float_as_uint(f);
  unsigned r = (u + 0x7fffu + ((u >> 16) & 1u)) >> 16;  // RNE
  return (unsigned short)r;
}
static __device__ __forceinline__ float bflo(unsigned u) {  // low ushort -> float
  return __uint_as_float(u << 16);
}
static __device__ __forceinline__ float bfhi(unsigned u) {  // high ushort -> float
  return __uint_as_float(u & 0xffff0000u);
}

// ---------------------------------------------------------------------------
// Cast x (fp32 [N][128]) -> bf16 same layout
// ---------------------------------------------------------------------------
__global__ void castx_kernel(const float* __restrict__ x,
                             unsigned short* __restrict__ xb, int total4) {
  int i = blockIdx.x * 256 + threadIdx.x;
  if (i < total4) {
    float4 f = *(const float4*)&x[i * 4];
    ushort4 o;
    o.x = f2bf(f.x); o.y = f2bf(f.y); o.z = f2bf(f.z); o.w = f2bf(f.w);
    *(ushort4*)&xb[i * 4] = o;
  }
}

// Cast + transpose W (fp32 [128][M]) -> bf16 Wt [M][128]
__global__ void castwt_kernel(const float* __restrict__ W,
                              unsigned short* __restrict__ Wt,
                              int mlog2, int total) {
  int i = blockIdx.x * 256 + threadIdx.x;
  if (i < total) {
    int M1 = (1 << mlog2) - 1;
    int m = i & M1;
    int kk = i >> mlog2;
    Wt[m * 128 + kk] = f2bf(W[i]);
  }
}

// ---------------------------------------------------------------------------
// MFMA GEMM: out[N x M] = Xb[N x 128](bf16) @ Wt[M x 128]^T(bf16) + bias
// 128x128 tile, 4 waves 2x2. BF16OUT selects bf16 vs fp32 output.
// ---------------------------------------------------------------------------
template <bool BF16OUT>
__global__ __launch_bounds__(256) void gemm_mfma_kernel(
    const unsigned short* __restrict__ Xb, const unsigned short* __restrict__ Wt,
    const float* __restrict__ bias, void* __restrict__ outp, int N, int M) {
  __shared__ unsigned short Xs[128][72];
  __shared__ unsigned short Ws[128][72];
  const int row0 = blockIdx.x * 128;
  const int col0 = blockIdx.y * 128;
  const int tid = threadIdx.x;
  const int wave = tid >> 6, lane = tid & 63;
  const int wr = (wave >> 1) * 64, wc = (wave & 1) * 64;
  const int l16 = lane & 15, quad = lane >> 4;

  f32x4 acc[4][4] = {};

  for (int kc = 0; kc < 128; kc += 64) {
#pragma unroll
    for (int c = tid; c < 1024; c += 256) {
      int r = c >> 3;
      int k8 = (c & 7) * 8;
      int gr = row0 + r;
      int4 a = {0, 0, 0, 0};
      if (gr < N) a = *(const int4*)&Xb[(size_t)gr * 128 + kc + k8];
      *(int4*)&Xs[r][k8] = a;
      int gc = col0 + r;
      *(int4*)&Ws[r][k8] = *(const int4*)&Wt[(size_t)gc * 128 + kc + k8];
    }
    __syncthreads();
#pragma unroll
    for (int ks = 0; ks < 2; ++ks) {
      int k0 = ks * 32 + quad * 8;
      bf16x8 a[4], b[4];
#pragma unroll
      for (int i = 0; i < 4; ++i) a[i] = *(const bf16x8*)&Xs[wr + i * 16 + l16][k0];
#pragma unroll
      for (int j = 0; j < 4; ++j) b[j] = *(const bf16x8*)&Ws[wc + j * 16 + l16][k0];
#pragma unroll
      for (int i = 0; i < 4; ++i)
#pragma unroll
        for (int j = 0; j < 4; ++j)
          acc[i][j] = __builtin_amdgcn_mfma_f32_16x16x32_bf16(a[i], b[j], acc[i][j], 0, 0, 0);
    }
    __syncthreads();
  }
  // C/D layout: col = lane&15, row = quad*4 + reg
#pragma unroll
  for (int i = 0; i < 4; ++i) {
#pragma unroll
    for (int reg = 0; reg < 4; ++reg) {
      int r = row0 + wr + i * 16 + quad * 4 + reg;
      if (r < N) {
#pragma unroll
        for (int j = 0; j < 4; ++j) {
          int cidx = col0 + wc + j * 16 + l16;
          float val = acc[i][j][reg] + bias[cidx];
          if (BF16OUT)
            ((unsigned short*)outp)[(size_t)r * M + cidx] = f2bf(val);
          else
            ((float*)outp)[(size_t)r * M + cidx] = val;
        }
      }
    }
  }
}

// ---------------------------------------------------------------------------
// Edge bucketing
// ---------------------------------------------------------------------------
__global__ void hist_kernel(const int* __restrict__ dst, int* __restrict__ cnt, int E) {
  int e = blockIdx.x * 256 + threadIdx.x;
  if (e < E) atomicAdd(&cnt[dst[e]], 1);
}

// two-level scan: per-block local exclusive scan + block sums
__global__ __launch_bounds__(256) void scan1_kernel(const int* __restrict__ cnt,
                                                    int* __restrict__ off,
                                                    int* __restrict__ bsum, int n) {
  __shared__ int wsum[4];
  int tid = threadIdx.x;
  int i = blockIdx.x * 256 + tid;
  int lane = tid & 63, w = tid >> 6;
  int v = (i < n) ? cnt[i] : 0;
  int x = v;
#pragma unroll
  for (int d = 1; d < 64; d <<= 1) {
    int y = __shfl_up(x, d);
    if (lane >= d) x += y;
  }
  if (lane == 63) wsum[w] = x;
  __syncthreads();
  int wo = 0;
  for (int j = 0; j < w; ++j) wo += wsum[j];
  if (i < n) off[i] = wo + x - v;
  if (tid == 255) bsum[blockIdx.x] = wo + x;
}

__global__ void scan2_kernel(const int* __restrict__ bsum, int* __restrict__ boff,
                             int* __restrict__ off, int nb, int n) {
  int tid = threadIdx.x;  // 64 threads, nb <= 64
  int v = (tid < nb) ? bsum[tid] : 0;
  int x = v;
#pragma unroll
  for (int d = 1; d < 64; d <<= 1) {
    int y = __shfl_up(x, d);
    if (tid >= d) x += y;
  }
  if (tid < nb) boff[tid] = x - v;
  if (tid == 63) off[n] = x;  // grand total
}

__global__ void scan3_kernel(int* __restrict__ off, const int* __restrict__ boff, int n) {
  int i = blockIdx.x * 256 + threadIdx.x;
  if (i < n) off[i] += boff[blockIdx.x];
}

__global__ void scatter_kernel(const int* __restrict__ src, const int* __restrict__ dst,
                               const int* __restrict__ off, int* __restrict__ cur,
                               int* __restrict__ bsrc, int E) {
  int e = blockIdx.x * 256 + threadIdx.x;
  if (e < E) {
    int d = dst[e];
    int p = off[d] + atomicAdd(&cur[d], 1);
    bsrc[p] = src[e];
  }
}

// ---------------------------------------------------------------------------
// Attention (bf16 q/k/v): block = dst node, wave = head.
// Lane owns cols 2*lane, 2*lane+1 -> one dword load per row. 4-edge unroll.
// ---------------------------------------------------------------------------
__global__ __launch_bounds__(256) void attn_kernel(
    const unsigned short* __restrict__ qb, const unsigned short* __restrict__ kb,
    const unsigned short* __restrict__ vb, const int* __restrict__ off,
    const int* __restrict__ bsrc, float* __restrict__ outa, int N) {
  int node = blockIdx.x;
  int tid = threadIdx.x;
  int h = tid >> 6;
  int lane = tid & 63;
  const unsigned* qp = (const unsigned*)(qb + (size_t)node * HC_DIM + h * 128);
  unsigned qu = qp[lane];
  float q0 = bflo(qu), q1 = bfhi(qu);
  int beg = off[node], end = off[node + 1];
  const float scale = 0.08838834764831845f;  // 1/sqrt(128)
  float m = -INFINITY, lsum = 0.f, o0 = 0.f, o1 = 0.f;
  int idx = beg;
  for (; idx + 4 <= end; idx += 4) {
    int s0 = bsrc[idx], s1 = bsrc[idx + 1], s2 = bsrc[idx + 2], s3 = bsrc[idx + 3];
    unsigned ku0 = ((const unsigned*)(kb + (size_t)s0 * HC_DIM + h * 128))[lane];
    unsigned ku1 = ((const unsigned*)(kb + (size_t)s1 * HC_DIM + h * 128))[lane];
    unsigned ku2 = ((const unsigned*)(kb + (size_t)s2 * HC_DIM + h * 128))[lane];
    unsigned ku3 = ((const unsigned*)(kb + (size_t)s3 * HC_DIM + h * 128))[lane];
    unsigned vu0 = ((const unsigned*)(vb + (size_t)s0 * HC_DIM + h * 128))[lane];
    unsigned vu1 = ((const unsigned*)(vb + (size_t)s1 * HC_DIM + h * 128))[lane];
    unsigned vu2 = ((const unsigned*)(vb + (size_t)s2 * HC_DIM + h * 128))[lane];
    unsigned vu3 = ((const unsigned*)(vb + (size_t)s3 * HC_DIM + h * 128))[lane];
    float p0 = q0 * bflo(ku0) + q1 * bfhi(ku0);
    float p1 = q0 * bflo(ku1) + q1 * bfhi(ku1);
    float p2 = q0 * bflo(ku2) + q1 * bfhi(ku2);
    float p3 = q0 * bflo(ku3) + q1 * bfhi(ku3);
#pragma unroll
    for (int dmask = 1; dmask < 64; dmask <<= 1) {
      p0 += __shfl_xor(p0, dmask);
      p1 += __shfl_xor(p1, dmask);
      p2 += __shfl_xor(p2, dmask);
      p3 += __shfl_xor(p3, dmask);
    }
    float a0 = p0 * scale, a1 = p1 * scale, a2 = p2 * scale, a3 = p3 * scale;
    float mnew = fmaxf(fmaxf(fmaxf(a0, a1), fmaxf(a2, a3)), m);
    float corr = __expf(m - mnew);
    float w0 = __expf(a0 - mnew), w1 = __expf(a1 - mnew);
    float w2 = __expf(a2 - mnew), w3 = __expf(a3 - mnew);
    lsum = lsum * corr + (w0 + w1) + (w2 + w3);
    o0 = o0 * corr + w0 * bflo(vu0) + w1 * bflo(vu1) + w2 * bflo(vu2) + w3 * bflo(vu3);
    o1 = o1 * corr + w0 * bfhi(vu0) + w1 * bfhi(vu1) + w2 * bfhi(vu2) + w3 * bfhi(vu3);
    m = mnew;
  }
  for (; idx < end; ++idx) {
    int s = bsrc[idx];
    unsigned ku = ((const unsigned*)(kb + (size_t)s * HC_DIM + h * 128))[lane];
    unsigned vu = ((const unsigned*)(vb + (size_t)s * HC_DIM + h * 128))[lane];
    float p = q0 * bflo(ku) + q1 * bfhi(ku);
#pragma unroll
    for (int dmask = 1; dmask < 64; dmask <<= 1) p += __shfl_xor(p, dmask);
    float alpha = p * scale;
    float mnew = fmaxf(m, alpha);
    float corr = __expf(m - mnew);
    float w = __expf(alpha - mnew);
    lsum = lsum * corr + w;
    o0 = o0 * corr + w * bflo(vu);
    o1 = o1 * corr + w * bfhi(vu);
    m = mnew;
  }
  float den = lsum + 1e-16f;
  o0 /= den;
  o1 /= den;
  __shared__ float tmp[4][128];
  *(float2*)&tmp[h][lane * 2] = make_float2(o0, o1);
  __syncthreads();
  if (tid < 128) {
    float s = 0.25f * (tmp[0][tid] + tmp[1][tid] + tmp[2][tid] + tmp[3][tid]);
    outa[(size_t)node * 128 + tid] = s;
  }
}

// ---------------------------------------------------------------------------
// beta gate + out2 + column sums. Wave-per-row: shfl-only, no barriers.
// ---------------------------------------------------------------------------
__global__ __launch_bounds__(256) void combine_kernel(
    const float* __restrict__ outa, const float* __restrict__ skip,
    const float* __restrict__ Wbeta, float* __restrict__ out2,
    float* __restrict__ colsum, float* __restrict__ colsq, int N) {
  int tid = threadIdx.x;
  int lane = tid & 63, w = tid >> 6;
  float wb0a = Wbeta[lane],       wb0b = Wbeta[lane + 64];
  float wb1a = Wbeta[128 + lane], wb1b = Wbeta[192 + lane];
  float wb2a = Wbeta[256 + lane], wb2b = Wbeta[320 + lane];
  float cs0 = 0.f, cq0 = 0.f, cs1 = 0.f, cq1 = 0.f;
  for (int n = blockIdx.x * 4 + w; n < N; n += gridDim.x * 4) {
    float a0 = outa[(size_t)n * 128 + lane];
    float a1 = outa[(size_t)n * 128 + lane + 64];
    float s0 = skip[(size_t)n * 128 + lane];
    float s1 = skip[(size_t)n * 128 + lane + 64];
    float p = a0 * wb0a + s0 * wb1a + (a0 - s0) * wb2a +
              a1 * wb0b + s1 * wb1b + (a1 - s1) * wb2b;
#pragma unroll
    for (int dmask = 1; dmask < 64; dmask <<= 1) p += __shfl_xor(p, dmask);
    float beta = 1.f / (1.f + __expf(-p));
    float o0 = beta * s0 + (1.f - beta) * a0;
    float o1 = beta * s1 + (1.f - beta) * a1;
    out2[(size_t)n * 128 + lane] = o0;
    out2[(size_t)n * 128 + lane + 64] = o1;
    cs0 += o0; cq0 += o0 * o0;
    cs1 += o1; cq1 += o1 * o1;
  }
  atomicAdd(&colsum[lane], cs0);
  atomicAdd(&colsum[lane + 64], cs1);
  atomicAdd(&colsq[lane], cq0);
  atomicAdd(&colsq[lane + 64], cq1);
}

// var = E[o^2] - mean^2 * s * (2 - s)  (exact expansion with gn_mean_scale)
__global__ void stats_kernel(const float* __restrict__ colsum,
                             const float* __restrict__ colsq,
                             const float* __restrict__ gnw,
                             const float* __restrict__ gnb,
                             const float* __restrict__ gnms,
                             float* __restrict__ fin, int N) {
  int t = threadIdx.x;
  float invN = 1.f / (float)N;
  float mean = colsum[t] * invN;
  float Es = colsq[t] * invN;
  float s = gnms[t];
  float var = Es - mean * mean * s * (2.f - s);
  float inv = 1.f / sqrtf(var + 1e-5f);
  fin[t] = s * mean;
  fin[128 + t] = gnw[t] * inv;
  fin[256 + t] = gnb[t];
}

__global__ void final_kernel(const float* __restrict__ out2,
                             const float* __restrict__ fin,
                             const float* __restrict__ x,
                             float* __restrict__ y, int total) {
  int i = blockIdx.x * 256 + threadIdx.x;
  if (i < total) {
    int c = i & 127;
    float o = out2[i];
    float t = (o - fin[c]) * fin[128 + c] + fin[256 + c];
    float g = 0.5f * t * (1.f + erff(t * 0.70710678118654752f));
    y[i] = g + x[i];
  }
}

extern "C" void kernel_launch(void* const* d_in, const int* in_sizes, int n_in,
                              void* d_out, int out_size, void* d_ws, size_t ws_size,
                              hipStream_t stream) {
  const float* x     = (const float*)d_in[0];
  const int*   ei    = (const int*)d_in[1];
  const float* Wq    = (const float*)d_in[2];
  const float* bq    = (const float*)d_in[3];
  const float* Wk    = (const float*)d_in[4];
  const float* bk    = (const float*)d_in[5];
  const float* Wv    = (const float*)d_in[6];
  const float* bv    = (const float*)d_in[7];
  const float* Wskip = (const float*)d_in[8];
  const float* bskip = (const float*)d_in[9];
  const float* Wbeta = (const float*)d_in[10];
  const float* gnw   = (const float*)d_in[11];
  const float* gnb   = (const float*)d_in[12];
  const float* gnms  = (const float*)d_in[13];

  const int N = in_sizes[0] / D_DIM;   // 10000
  const int E = in_sizes[1] / 2;       // 160000
  const int* src = ei;
  const int* dst = ei + E;

  // workspace carve-up
  char* p = (char*)d_ws;
  unsigned short* qb = (unsigned short*)p; p += (size_t)N * HC_DIM * 2;
  unsigned short* kb = (unsigned short*)p; p += (size_t)N * HC_DIM * 2;
  unsigned short* vbuf = (unsigned short*)p; p += (size_t)N * HC_DIM * 2;
  float* skip = (float*)p; p += (size_t)N * D_DIM * 4;
  float* outa = (float*)p; p += (size_t)N * D_DIM * 4;
  float* out2 = (float*)p; p += (size_t)N * D_DIM * 4;
  float* colsum = (float*)p; p += 128 * 4;
  float* colsq  = (float*)p; p += 128 * 4;
  float* fin    = (float*)p; p += 384 * 4;
  int* cnt  = (int*)p; p += (size_t)N * 4;
  int* off  = (int*)p; p += (size_t)(N + 1) * 4;
  int* cur  = (int*)p; p += (size_t)N * 4;
  int* bsum = (int*)p; p += 64 * 4;
  int* boff = (int*)p; p += 64 * 4;
  int* bsrc = (int*)p; p += (size_t)E * 4;
  unsigned short* xb  = (unsigned short*)p; p += (size_t)N * D_DIM * 2;
  unsigned short* wtq = (unsigned short*)p; p += (size_t)HC_DIM * 128 * 2;
  unsigned short* wtk = (unsigned short*)p; p += (size_t)HC_DIM * 128 * 2;
  unsigned short* wtv = (unsigned short*)p; p += (size_t)HC_DIM * 128 * 2;
  unsigned short* wts = (unsigned short*)p; p += (size_t)128 * 128 * 2;

  hipMemsetAsync(cnt, 0, (size_t)N * 4, stream);
  hipMemsetAsync(cur, 0, (size_t)N * 4, stream);
  hipMemsetAsync(colsum, 0, 128 * 4, stream);
  hipMemsetAsync(colsq, 0, 128 * 4, stream);

  // casts
  int x4 = N * D_DIM / 4;
  castx_kernel<<<(x4 + 255) / 256, 256, 0, stream>>>(x, xb, x4);
  castwt_kernel<<<(128 * HC_DIM + 255) / 256, 256, 0, stream>>>(Wq, wtq, 9, 128 * HC_DIM);
  castwt_kernel<<<(128 * HC_DIM + 255) / 256, 256, 0, stream>>>(Wk, wtk, 9, 128 * HC_DIM);
  castwt_kernel<<<(128 * HC_DIM + 255) / 256, 256, 0, stream>>>(Wv, wtv, 9, 128 * HC_DIM);
  castwt_kernel<<<(128 * 128 + 255) / 256, 256, 0, stream>>>(Wskip, wts, 7, 128 * 128);

  const int rowBlocks = (N + 127) / 128;  // 79

  // projections (MFMA); q/k/v stored bf16, skip fp32
  gemm_mfma_kernel<true><<<dim3(rowBlocks, HC_DIM / 128), 256, 0, stream>>>(xb, wtq, bq, qb, N, HC_DIM);
  gemm_mfma_kernel<true><<<dim3(rowBlocks, HC_DIM / 128), 256, 0, stream>>>(xb, wtk, bk, kb, N, HC_DIM);
  gemm_mfma_kernel<true><<<dim3(rowBlocks, HC_DIM / 128), 256, 0, stream>>>(xb, wtv, bv, vbuf, N, HC_DIM);
  gemm_mfma_kernel<false><<<dim3(rowBlocks, 1), 256, 0, stream>>>(xb, wts, bskip, skip, N, D_DIM);

  // bucket edges by dst (two-level scan)
  int eBlocks = (E + 255) / 256;
  int nBlocks = (N + 255) / 256;  // 40 <= 64
  hist_kernel<<<eBlocks, 256, 0, stream>>>(dst, cnt, E);
  scan1_kernel<<<nBlocks, 256, 0, stream>>>(cnt, off, bsum, N);
  scan2_kernel<<<1, 64, 0, stream>>>(bsum, boff, off, nBlocks, N);
  scan3_kernel<<<nBlocks, 256, 0, stream>>>(off, boff, N);
  scatter_kernel<<<eBlocks, 256, 0, stream>>>(src, dst, off, cur, bsrc, E);

  // attention
  attn_kernel<<<N, 256, 0, stream>>>(qb, kb, vbuf, off, bsrc, outa, N);

  // beta gate + column moments
  combine_kernel<<<160, 256, 0, stream>>>(outa, skip, Wbeta, out2, colsum, colsq, N);

  // stats + finalize
  stats_kernel<<<1, 128, 0, stream>>>(colsum, colsq, gnw, gnb, gnms, fin, N);
  int total = N * D_DIM;
  final_kernel<<<(total + 255) / 256, 256, 0, stream>>>(out2, fin, x, (float*)d_out, total);
}